// Round 6
// baseline (1062.399 us; speedup 1.0000x reference)
//
#include <hip/hip_runtime.h>

#define D_DIM 256
#define K_CODES 1024
#define T_DIM 4096
#define MTILE 128
#define NCHUNK 32
#define NCHUNKS (K_CODES / NCHUNK)          // 32
#define PART_BYTES (NCHUNK * D_DIM * 2)     // 16384 (one f16 part of a chunk)
#define CHUNK_BYTES (2 * PART_BYTES)        // 32768 (hi+lo)

typedef _Float16 f16x8 __attribute__((ext_vector_type(8)));
typedef float    f32x4 __attribute__((ext_vector_type(4)));

// ws layout: [0,4096): eN f32[1024]; [4096, 4096+1 MiB): swizzled E image (f16 hi/lo)

// --- prep 1: eN[k] = ||E[k]||^2 (fp64 accum) ---
__global__ __launch_bounds__(256) void vq_norm_kernel(const float* __restrict__ E,
                                                      float* __restrict__ eN) {
    __shared__ double wsum[4];
    const int k = blockIdx.x;
    const int tid = threadIdx.x;
    float v = E[(size_t)k * D_DIM + tid];
    double s = (double)v * (double)v;
    #pragma unroll
    for (int off = 32; off > 0; off >>= 1)
        s += __shfl_down(s, off);
    if ((tid & 63) == 0) wsum[tid >> 6] = s;
    __syncthreads();
    if (tid == 0) eN[k] = (float)((wsum[0] + wsum[1]) + (wsum[2] + wsum[3]));
}

// --- prep 2: E -> f16 hi/lo, stored as the pre-swizzled LDS chunk image ---
__global__ __launch_bounds__(256) void vq_prep_e(const float* __restrict__ E,
                                                 char* __restrict__ img) {
    const int g  = blockIdx.x * 256 + threadIdx.x;   // 0..32767
    const int k  = g >> 5;                           // code 0..1023
    const int dg = g & 31;                           // d-group of 8
    const float* src = E + (size_t)k * D_DIM + dg * 8;
    f16x8 hi, lo;
    #pragma unroll
    for (int j = 0; j < 8; ++j) {
        float v = src[j];
        _Float16 h = (_Float16)v;
        hi[j] = h;
        lo[j] = (_Float16)(v - (float)h);
    }
    const int chunk = k >> 5, code = k & 31;
    size_t off = (size_t)chunk * CHUNK_BYTES + code * 512 + ((dg * 16) ^ ((code & 7) << 4));
    *(f16x8*)(img + off) = hi;
    *(f16x8*)(img + off + PART_BYTES) = lo;
}

__device__ __forceinline__ void stage_chunk(const char* gsrc, char* ldsdst, int tid) {
    const int lane = tid & 63;
    const int woff = (tid >> 6) << 10;   // wave*1024
    #pragma unroll
    for (int r = 0; r < 8; ++r) {
        __builtin_amdgcn_global_load_lds(
            (const __attribute__((address_space(1))) void*)(gsrc + r * 4096 + woff + (size_t)lane * 16),
            (__attribute__((address_space(3))) void*)(ldsdst + r * 4096 + woff),
            16, 0, 0);
    }
}

// Single-buffered E chunk: 36.5 KiB LDS -> 4 blocks/CU (16 waves/CU, 4/SIMD).
// Overlap across chunks comes from the 4 independent co-resident blocks,
// not from intra-block double-buffering (which capped us at 2 waves/SIMD).
__global__ __launch_bounds__(256, 4) void vq_mfma_kernel(const float* __restrict__ z,
                                                         const float* __restrict__ E,
                                                         const float* __restrict__ eN_g,
                                                         const char* __restrict__ imgE,
                                                         float* __restrict__ out) {
    __shared__ __align__(16) char lds_all[CHUNK_BYTES + 4096 + 512];
    char*  lds_e = lds_all;
    float* eN_s  = (float*)(lds_all + CHUNK_BYTES);
    int*   idx_s = (int*)(lds_all + CHUNK_BYTES + 4096);

    const int tid  = threadIdx.x;
    const int lane = tid & 63;
    const int w    = tid >> 6;        // wave 0..3
    const int l15  = lane & 15;
    const int kg   = lane >> 4;       // 0..3
    const int bb   = blockIdx.y;
    const int t0   = blockIdx.x * MTILE;

    // ---- A fragments: z loaded straight from global (coalesced), f16 hi/lo split
    const float* zb = z + (size_t)bb * D_DIM * T_DIM + t0;
    f16x8 a_hi[2][8], a_lo[2][8];
    #pragma unroll
    for (int s = 0; s < 2; ++s) {
        const int tcol = w * 32 + s * 16 + l15;
        #pragma unroll
        for (int ks = 0; ks < 8; ++ks) {
            #pragma unroll
            for (int j = 0; j < 8; ++j) {
                float v = zb[(size_t)(ks * 32 + kg * 8 + j) * T_DIM + tcol];
                _Float16 h = (_Float16)v;
                a_hi[s][ks][j] = h;
                a_lo[s][ks][j] = (_Float16)(v - (float)h);
            }
        }
    }

    // ---- stage eN
    for (int i = tid; i < K_CODES; i += 256) eN_s[i] = eN_g[i];

    float best[2][4];
    int   bestk[2][4];
    #pragma unroll
    for (int s = 0; s < 2; ++s)
        #pragma unroll
        for (int r = 0; r < 4; ++r) { best[s][r] = __builtin_huge_valf(); bestk[s][r] = 0; }

    for (int c = 0; c < NCHUNKS; ++c) {
        __syncthreads();   // all waves done reading lds_e from previous chunk
        stage_chunk(imgE + (size_t)c * CHUNK_BYTES, lds_e, tid);
        __syncthreads();   // drains vmcnt -> chunk staged

        #pragma unroll
        for (int nt = 0; nt < 2; ++nt) {
            const int  cl    = nt * 16 + l15;
            const int  swz   = (cl & 7) << 4;
            const char* bbase = lds_e + cl * 512;

            // per-lane code norm, loaded BEFORE the MFMA cluster (latency hidden)
            const float en = eN_s[c * NCHUNK + cl];

            // 6 independent accumulator chains: [strip][pass]
            f32x4 aH[2], aM[2], aL[2];
            #pragma unroll
            for (int s = 0; s < 2; ++s) {
                aH[s] = (f32x4){0.f, 0.f, 0.f, 0.f};
                aM[s] = (f32x4){0.f, 0.f, 0.f, 0.f};
                aL[s] = (f32x4){0.f, 0.f, 0.f, 0.f};
            }

            __builtin_amdgcn_s_setprio(1);
            #pragma unroll
            for (int ks = 0; ks < 8; ++ks) {
                const int ko = (ks * 64 + kg * 16) ^ swz;
                f16x8 bh = *(const f16x8*)(bbase + ko);
                f16x8 bl = *(const f16x8*)(bbase + ko + PART_BYTES);
                #pragma unroll
                for (int s = 0; s < 2; ++s)
                    aH[s] = __builtin_amdgcn_mfma_f32_16x16x32_f16(a_hi[s][ks], bh, aH[s], 0, 0, 0);
                #pragma unroll
                for (int s = 0; s < 2; ++s)
                    aM[s] = __builtin_amdgcn_mfma_f32_16x16x32_f16(a_hi[s][ks], bl, aM[s], 0, 0, 0);
                #pragma unroll
                for (int s = 0; s < 2; ++s)
                    aL[s] = __builtin_amdgcn_mfma_f32_16x16x32_f16(a_lo[s][ks], bh, aL[s], 0, 0, 0);
            }
            __builtin_amdgcn_s_setprio(0);

            const int n = c * NCHUNK + cl;
            #pragma unroll
            for (int s = 0; s < 2; ++s) {
                f32x4 dsum = (aH[s] + aM[s]) + aL[s];
                #pragma unroll
                for (int r = 0; r < 4; ++r) {
                    float dist = fmaf(-2.0f, dsum[r], en);
                    // strict < with ascending n == first-min tie-break (matches jnp.argmin)
                    if (dist < best[s][r]) { best[s][r] = dist; bestk[s][r] = n; }
                }
            }
        }
    }

    // ---- cross-lane argmin reduce over the 16 columns (bits 0-3 of lane)
    #pragma unroll
    for (int off = 1; off < 16; off <<= 1) {
        #pragma unroll
        for (int s = 0; s < 2; ++s) {
            #pragma unroll
            for (int r = 0; r < 4; ++r) {
                float od = __shfl_xor(best[s][r], off, 64);
                int   ok = __shfl_xor(bestk[s][r], off, 64);
                if (od < best[s][r] || (od == best[s][r] && ok < bestk[s][r])) {
                    best[s][r] = od; bestk[s][r] = ok;
                }
            }
        }
    }
    __syncthreads();   // lds_e reads done; safe before idx_s writes (same alloc region)
    if (l15 == 0) {
        #pragma unroll
        for (int s = 0; s < 2; ++s)
            #pragma unroll
            for (int r = 0; r < 4; ++r)
                idx_s[w * 32 + s * 16 + kg * 4 + r] = bestk[s][r];
    }
    __syncthreads();

    // ---- fused gather: out[b][d][t0+p] = E[idx[p]][d]
    const int p  = tid & 127;
    const int dh = tid >> 7;
    const int kk = idx_s[p];
    const float* er = E + (size_t)kk * D_DIM + dh * 128;
    float* ob = out + (size_t)bb * D_DIM * T_DIM + t0 + p;
    #pragma unroll 8
    for (int i = 0; i < 128; ++i)
        ob[(size_t)(dh * 128 + i) * T_DIM] = er[i];
}

extern "C" void kernel_launch(void* const* d_in, const int* in_sizes, int n_in,
                              void* d_out, int out_size, void* d_ws, size_t ws_size,
                              hipStream_t stream) {
    const float* z = (const float*)d_in[0];
    const float* E = (const float*)d_in[1];
    float* out = (float*)d_out;
    float* eN  = (float*)d_ws;
    char*  img = (char*)d_ws + 4096;

    const int B = in_sizes[0] / (D_DIM * T_DIM);   // 32

    vq_norm_kernel<<<dim3(K_CODES), dim3(256), 0, stream>>>(E, eN);
    vq_prep_e<<<dim3((K_CODES * NCHUNK) / 256), dim3(256), 0, stream>>>(E, img);

    dim3 grid(T_DIM / MTILE, B);
    vq_mfma_kernel<<<grid, dim3(256), 0, stream>>>(z, E, eN, img, out);
}

// Round 7
// 207.010 us; speedup vs baseline: 5.1321x; 5.1321x over previous
//
#include <hip/hip_runtime.h>

#define D_DIM 256
#define K_CODES 1024
#define T_DIM 4096
#define MTILE 128
#define NCHUNK 32
#define NCHUNKS (K_CODES / NCHUNK)          // 32
#define PART_BYTES (NCHUNK * D_DIM * 2)     // 16384 (one f16 part of a chunk)
#define CHUNK_BYTES (2 * PART_BYTES)        // 32768 (hi+lo)

typedef _Float16 f16x8 __attribute__((ext_vector_type(8)));
typedef float    f32x4 __attribute__((ext_vector_type(4)));

// ws layout: [0,4096): eN f32[1024]; [4096, 4096+1 MiB): swizzled E image (f16 hi/lo)

// --- prep 1: eN[k] = ||E[k]||^2 (fp64 accum) ---
__global__ __launch_bounds__(256) void vq_norm_kernel(const float* __restrict__ E,
                                                      float* __restrict__ eN) {
    __shared__ double wsum[4];
    const int k = blockIdx.x;
    const int tid = threadIdx.x;
    float v = E[(size_t)k * D_DIM + tid];
    double s = (double)v * (double)v;
    #pragma unroll
    for (int off = 32; off > 0; off >>= 1)
        s += __shfl_down(s, off);
    if ((tid & 63) == 0) wsum[tid >> 6] = s;
    __syncthreads();
    if (tid == 0) eN[k] = (float)((wsum[0] + wsum[1]) + (wsum[2] + wsum[3]));
}

// --- prep 2: E -> f16 hi/lo, stored as the pre-swizzled LDS chunk image ---
__global__ __launch_bounds__(256) void vq_prep_e(const float* __restrict__ E,
                                                 char* __restrict__ img) {
    const int g  = blockIdx.x * 256 + threadIdx.x;   // 0..32767
    const int k  = g >> 5;                           // code 0..1023
    const int dg = g & 31;                           // d-group of 8
    const float* src = E + (size_t)k * D_DIM + dg * 8;
    f16x8 hi, lo;
    #pragma unroll
    for (int j = 0; j < 8; ++j) {
        float v = src[j];
        _Float16 h = (_Float16)v;
        hi[j] = h;
        lo[j] = (_Float16)(v - (float)h);
    }
    const int chunk = k >> 5, code = k & 31;
    size_t off = (size_t)chunk * CHUNK_BYTES + code * 512 + ((dg * 16) ^ ((code & 7) << 4));
    *(f16x8*)(img + off) = hi;
    *(f16x8*)(img + off + PART_BYTES) = lo;
}

__device__ __forceinline__ void stage_chunk(const char* gsrc, char* ldsdst, int tid) {
    const int lane = tid & 63;
    const int woff = (tid >> 6) << 10;   // wave*1024
    #pragma unroll
    for (int r = 0; r < 8; ++r) {
        __builtin_amdgcn_global_load_lds(
            (const __attribute__((address_space(1))) void*)(gsrc + r * 4096 + woff + (size_t)lane * 16),
            (__attribute__((address_space(3))) void*)(ldsdst + r * 4096 + woff),
            16, 0, 0);
    }
}

__global__ __launch_bounds__(256, 2) void vq_mfma_kernel(const float* __restrict__ z,
                                                         const float* __restrict__ E,
                                                         const float* __restrict__ eN_g,
                                                         const char* __restrict__ imgE,
                                                         float* __restrict__ out) {
    __shared__ __align__(16) char lds_all[2 * CHUNK_BYTES + 4096 + 512];
    char*  lds_e = lds_all;
    float* eN_s  = (float*)(lds_all + 2 * CHUNK_BYTES);
    int*   idx_s = (int*)(lds_all + 2 * CHUNK_BYTES + 4096);

    const int tid  = threadIdx.x;
    const int lane = tid & 63;
    const int w    = tid >> 6;        // wave 0..3
    const int l15  = lane & 15;
    const int kg   = lane >> 4;       // 0..3
    const int bb   = blockIdx.y;
    const int t0   = blockIdx.x * MTILE;

    // ---- A fragments: z loaded straight from global (coalesced), f16 hi/lo split.
    // These live in the AGPR half of the unified file (~128 regs) — do NOT
    // raise launch_bounds min-waves past 2 or they spill (round-6 lesson).
    const float* zb = z + (size_t)bb * D_DIM * T_DIM + t0;
    f16x8 a_hi[2][8], a_lo[2][8];
    #pragma unroll
    for (int s = 0; s < 2; ++s) {
        const int tcol = w * 32 + s * 16 + l15;
        #pragma unroll
        for (int ks = 0; ks < 8; ++ks) {
            #pragma unroll
            for (int j = 0; j < 8; ++j) {
                float v = zb[(size_t)(ks * 32 + kg * 8 + j) * T_DIM + tcol];
                _Float16 h = (_Float16)v;
                a_hi[s][ks][j] = h;
                a_lo[s][ks][j] = (_Float16)(v - (float)h);
            }
        }
    }

    // ---- stage eN + first E chunk, then one full-drain barrier (prologue only)
    for (int i = tid; i < K_CODES; i += 256) eN_s[i] = eN_g[i];
    stage_chunk(imgE, lds_e, tid);
    __syncthreads();   // drains vmcnt(0): chunk 0 staged, eN_s visible

    float best[2][4];
    int   bestk[2][4];
    #pragma unroll
    for (int s = 0; s < 2; ++s)
        #pragma unroll
        for (int r = 0; r < 4; ++r) { best[s][r] = __builtin_huge_valf(); bestk[s][r] = 0; }

    for (int c = 0; c < NCHUNKS; ++c) {
        const char* ebuf = lds_e + (c & 1) * CHUNK_BYTES;

        // T4 counted-vmcnt pipeline: issue next-chunk stage, wait ONLY for the
        // current chunk's loads (8 newest may stay in flight across the barrier).
        if (c + 1 < NCHUNKS) {
            stage_chunk(imgE + (size_t)(c + 1) * CHUNK_BYTES,
                        lds_e + ((c + 1) & 1) * CHUNK_BYTES, tid);
            asm volatile("s_waitcnt vmcnt(8)" ::: "memory");
        } else {
            asm volatile("s_waitcnt vmcnt(0)" ::: "memory");
        }
        __builtin_amdgcn_s_barrier();          // publish all waves' staged slices
        __builtin_amdgcn_sched_barrier(0);     // rule #18: no hoisting past the wait

        #pragma unroll
        for (int nt = 0; nt < 2; ++nt) {
            const int  cl    = nt * 16 + l15;
            const int  swz   = (cl & 7) << 4;
            const char* bbase = ebuf + cl * 512;

            // per-lane code norm, loaded BEFORE the MFMA cluster (latency hidden)
            const float en = eN_s[c * NCHUNK + cl];

            // 6 independent accumulator chains: [strip][pass]
            f32x4 aH[2], aM[2], aL[2];
            #pragma unroll
            for (int s = 0; s < 2; ++s) {
                aH[s] = (f32x4){0.f, 0.f, 0.f, 0.f};
                aM[s] = (f32x4){0.f, 0.f, 0.f, 0.f};
                aL[s] = (f32x4){0.f, 0.f, 0.f, 0.f};
            }

            __builtin_amdgcn_s_setprio(1);
            #pragma unroll
            for (int ks = 0; ks < 8; ++ks) {
                const int ko = (ks * 64 + kg * 16) ^ swz;
                f16x8 bh = *(const f16x8*)(bbase + ko);
                f16x8 bl = *(const f16x8*)(bbase + ko + PART_BYTES);
                #pragma unroll
                for (int s = 0; s < 2; ++s)
                    aH[s] = __builtin_amdgcn_mfma_f32_16x16x32_f16(a_hi[s][ks], bh, aH[s], 0, 0, 0);
                #pragma unroll
                for (int s = 0; s < 2; ++s)
                    aM[s] = __builtin_amdgcn_mfma_f32_16x16x32_f16(a_hi[s][ks], bl, aM[s], 0, 0, 0);
                #pragma unroll
                for (int s = 0; s < 2; ++s)
                    aL[s] = __builtin_amdgcn_mfma_f32_16x16x32_f16(a_lo[s][ks], bh, aL[s], 0, 0, 0);
            }
            __builtin_amdgcn_s_setprio(0);

            const int n = c * NCHUNK + cl;
            #pragma unroll
            for (int s = 0; s < 2; ++s) {
                f32x4 dsum = (aH[s] + aM[s]) + aL[s];
                #pragma unroll
                for (int r = 0; r < 4; ++r) {
                    float dist = fmaf(-2.0f, dsum[r], en);
                    // strict < with ascending n == first-min tie-break (matches jnp.argmin)
                    if (dist < best[s][r]) { best[s][r] = dist; bestk[s][r] = n; }
                }
            }
        }

        // my ds_reads of ebuf were consumed by MFMAs (lgkmcnt ordered) — safe
        // for other waves to overwrite ebuf after this barrier. vmcnt NOT drained.
        __builtin_amdgcn_sched_barrier(0);
        __builtin_amdgcn_s_barrier();
    }

    // ---- cross-lane argmin reduce over the 16 columns (bits 0-3 of lane)
    #pragma unroll
    for (int off = 1; off < 16; off <<= 1) {
        #pragma unroll
        for (int s = 0; s < 2; ++s) {
            #pragma unroll
            for (int r = 0; r < 4; ++r) {
                float od = __shfl_xor(best[s][r], off, 64);
                int   ok = __shfl_xor(bestk[s][r], off, 64);
                if (od < best[s][r] || (od == best[s][r] && ok < bestk[s][r])) {
                    best[s][r] = od; bestk[s][r] = ok;
                }
            }
        }
    }
    if (l15 == 0) {
        #pragma unroll
        for (int s = 0; s < 2; ++s)
            #pragma unroll
            for (int r = 0; r < 4; ++r)
                idx_s[w * 32 + s * 16 + kg * 4 + r] = bestk[s][r];
    }
    __syncthreads();

    // ---- fused gather: out[b][d][t0+p] = E[idx[p]][d]
    const int p  = tid & 127;
    const int dh = tid >> 7;
    const int kk = idx_s[p];
    const float* er = E + (size_t)kk * D_DIM + dh * 128;
    float* ob = out + (size_t)bb * D_DIM * T_DIM + t0 + p;
    #pragma unroll 8
    for (int i = 0; i < 128; ++i)
        ob[(size_t)(dh * 128 + i) * T_DIM] = er[i];
}

extern "C" void kernel_launch(void* const* d_in, const int* in_sizes, int n_in,
                              void* d_out, int out_size, void* d_ws, size_t ws_size,
                              hipStream_t stream) {
    const float* z = (const float*)d_in[0];
    const float* E = (const float*)d_in[1];
    float* out = (float*)d_out;
    float* eN  = (float*)d_ws;
    char*  img = (char*)d_ws + 4096;

    const int B = in_sizes[0] / (D_DIM * T_DIM);   // 32

    vq_norm_kernel<<<dim3(K_CODES), dim3(256), 0, stream>>>(E, eN);
    vq_prep_e<<<dim3((K_CODES * NCHUNK) / 256), dim3(256), 0, stream>>>(E, img);

    dim3 grid(T_DIM / MTILE, B);
    vq_mfma_kernel<<<grid, dim3(256), 0, stream>>>(z, E, eN, img, out);
}